// Round 1
// baseline (584.972 us; speedup 1.0000x reference)
//
#include <hip/hip_runtime.h>
#include <hip/hip_bf16.h>
#include <cstdint>

// Problem constants
#define BB 4
#define CC 512
#define CQK 64
#define HH 129
#define WW 129
#define HS 65
#define WSZ 65
#define NN 4225            // HS*WSZ
#define NP 4352            // padded N (34*128)
#define OUTSZ 34080768     // BB*CC*HH*WW
#define ESZ 17850625       // NN*NN

typedef unsigned short u16;
typedef __attribute__((ext_vector_type(8))) __bf16 bfrag;
typedef __attribute__((ext_vector_type(4))) float f4v;

__device__ inline u16 f2bf(float f) {
    union { float f; unsigned int u; } v; v.f = f;
    unsigned int u = v.u;
    return (u16)((u + 0x7FFFu + ((u >> 16) & 1u)) >> 16);
}

// ---------------- K0: cast & pack weights [640][512] bf16 (q rows 0-63, k 64-127, v 128-639)
__global__ __launch_bounds__(256) void cast_weights(const float* __restrict__ Wq,
                                                    const float* __restrict__ Wk,
                                                    const float* __restrict__ Wv,
                                                    u16* __restrict__ Wc) {
    int idx = blockIdx.x * 256 + threadIdx.x;
    if (idx >= 640 * 512) return;
    int o = idx >> 9, c = idx & 511;
    float v = (o < 64) ? Wq[o * 512 + c] : (o < 128) ? Wk[(o - 64) * 512 + c] : Wv[(o - 128) * 512 + c];
    Wc[idx] = f2bf(v);
}

// ---------------- K1: subsample (exact stride-2) + transpose to XsT[b][n][c] bf16
__global__ __launch_bounds__(256) void subsample_t(const float* __restrict__ x, u16* __restrict__ XsT) {
    __shared__ u16 tile[64][65];
    int nt = blockIdx.x, ct = blockIdx.y, b = blockIdx.z;
    int t = threadIdx.x;
#pragma unroll
    for (int l = 0; l < 16; ++l) {
        int e = t + l * 256;
        int ci = e >> 6, nj = e & 63;
        int n = nt * 64 + nj;
        int nc = n < (NN - 1) ? n : (NN - 1);
        int i = nc / 65, j = nc % 65;
        int c = ct * 64 + ci;
        float v = x[(((size_t)b * CC + c) * HH + 2 * i) * WW + 2 * j];
        tile[ci][nj] = f2bf(v);
    }
    __syncthreads();
#pragma unroll
    for (int l = 0; l < 16; ++l) {
        int e = t + l * 256;
        int nj = e >> 6, ci = e & 63;
        XsT[((size_t)b * NP + nt * 64 + nj) * 512 + ct * 64 + ci] = tile[ci][nj];
    }
}

// ---------------- generic NT GEMM: C[m][n] = sum_k A[m][k]*Bt[n][k]
// MODE 0: QKV  A=Wc[640][512], B=XsT[b], out -> qkT[n][o] (o<128) / V[o-128][n], +bias, bf16
// MODE 1: energy A=qkT[b] cols0-63, B=qkT[b] cols64-127, K=64, out -> energy fp32 (bounded 4225)
// MODE 2: PV   A=V[b][512][NP], B=P[b][NP][NP], K=NP, out -> ctx fp32 [512][NP]
template <int MODE>
__global__ __launch_bounds__(256) void gemm_nt(const u16* __restrict__ Abase,
                                               const u16* __restrict__ Bbase,
                                               int K, int lda, int ldb,
                                               float* __restrict__ outF,
                                               u16* __restrict__ out1, u16* __restrict__ out2,
                                               const float* __restrict__ bq,
                                               const float* __restrict__ bk,
                                               const float* __restrict__ bv) {
    __shared__ __align__(16) u16 As[128 * 72];
    __shared__ __align__(16) u16 Bs[128 * 72];

    const int z = blockIdx.z;
    const u16* A; const u16* Bm;
    if (MODE == 0) { A = Abase;                          Bm = Bbase + (size_t)z * NP * 512; }
    if (MODE == 1) { A = Abase + (size_t)z * NP * 128;   Bm = Bbase + (size_t)z * NP * 128 + 64; }
    if (MODE == 2) { A = Abase + (size_t)z * 512 * NP;   Bm = Bbase + (size_t)z * NP * NP; }

    const size_t m0 = (size_t)blockIdx.y * 128;
    const size_t n0 = (size_t)blockIdx.x * 128;
    const u16* Ab = A + m0 * lda;
    const u16* Bb = Bm + n0 * ldb;

    const int tid = threadIdx.x;
    const int lane = tid & 63, w = tid >> 6;
    const int wr = w >> 1, wc = w & 1;
    const int frow = lane & 15, fk = (lane >> 4) * 8;

    f4v acc[4][4];
#pragma unroll
    for (int i = 0; i < 4; ++i)
#pragma unroll
        for (int j = 0; j < 4; ++j) acc[i][j] = (f4v){0.f, 0.f, 0.f, 0.f};

    for (int kt = 0; kt < K; kt += 64) {
        __syncthreads();
#pragma unroll
        for (int it = 0; it < 4; ++it) {
            int chunk = tid + it * 256;
            int r = chunk >> 3, kc = chunk & 7;
            *(int4*)&As[r * 72 + kc * 8] = *(const int4*)(Ab + (size_t)r * lda + kt + kc * 8);
            *(int4*)&Bs[r * 72 + kc * 8] = *(const int4*)(Bb + (size_t)r * ldb + kt + kc * 8);
        }
        __syncthreads();
#pragma unroll
        for (int ks = 0; ks < 2; ++ks) {
            bfrag af[4], bf[4];
#pragma unroll
            for (int i = 0; i < 4; ++i)
                af[i] = *(const bfrag*)&As[(wr * 64 + i * 16 + frow) * 72 + ks * 32 + fk];
#pragma unroll
            for (int j = 0; j < 4; ++j)
                bf[j] = *(const bfrag*)&Bs[(wc * 64 + j * 16 + frow) * 72 + ks * 32 + fk];
#pragma unroll
            for (int i = 0; i < 4; ++i)
#pragma unroll
                for (int j = 0; j < 4; ++j)
                    acc[i][j] = __builtin_amdgcn_mfma_f32_16x16x32_bf16(af[i], bf[j], acc[i][j], 0, 0, 0);
        }
    }

    // epilogue
    const int rbase = (lane >> 4) * 4, cbase = lane & 15;
    float* outFb = nullptr; u16* out1b = nullptr; u16* out2b = nullptr;
    if (MODE == 0) { out1b = out1 + (size_t)z * NP * 128; out2b = out2 + (size_t)z * 512 * NP; }
    if (MODE == 1) { outFb = outF + (size_t)z * ESZ; }
    if (MODE == 2) { outFb = outF + (size_t)z * 512 * NP; }

#pragma unroll
    for (int i = 0; i < 4; ++i)
#pragma unroll
        for (int j = 0; j < 4; ++j) {
            size_t row0 = m0 + wr * 64 + i * 16 + rbase;
            size_t col = n0 + wc * 64 + j * 16 + cbase;
#pragma unroll
            for (int r = 0; r < 4; ++r) {
                float v = acc[i][j][r];
                size_t ro = row0 + r;
                if (MODE == 0) {
                    int o = (int)ro;
                    float bias = (o < 64) ? bq[o] : (o < 128) ? bk[o - 64] : bv[o - 128];
                    u16 bb = f2bf(v + bias);
                    if (o < 128) out1b[col * 128 + o] = bb;
                    else out2b[(size_t)(o - 128) * NP + col] = bb;
                } else if (MODE == 1) {
                    if (ro < NN && col < NN) outFb[ro * NN + col] = v;
                } else {
                    outFb[ro * NP + col] = v;
                }
            }
        }
}

// ---------------- K4: row softmax -> normalized P bf16, m-padded with zeros
__global__ __launch_bounds__(256) void softmax_rows(const float* __restrict__ e, u16* __restrict__ P) {
    const int n = blockIdx.x, b = blockIdx.y;
    const float* row = e + (size_t)b * ESZ + (size_t)n * NN;
    u16* prow = P + ((size_t)b * NP + n) * NP;
    const int t = threadIdx.x;
    const int lane = t & 63, w = t >> 6;
    __shared__ float redmax[4], redsum[4];

    float vals[17];
    float m = -1e30f;
#pragma unroll
    for (int i = 0; i < 17; ++i) {
        int mm = i * 256 + t;
        vals[i] = (mm < NN) ? row[mm] : -1e30f;
        m = fmaxf(m, vals[i]);
    }
#pragma unroll
    for (int off = 32; off > 0; off >>= 1) m = fmaxf(m, __shfl_xor(m, off));
    if (lane == 0) redmax[w] = m;
    __syncthreads();
    m = fmaxf(fmaxf(redmax[0], redmax[1]), fmaxf(redmax[2], redmax[3]));

    float s = 0.f;
#pragma unroll
    for (int i = 0; i < 17; ++i) {
        int mm = i * 256 + t;
        if (mm < NN) { vals[i] = __expf(vals[i] - m); s += vals[i]; }
        else vals[i] = 0.f;
    }
#pragma unroll
    for (int off = 32; off > 0; off >>= 1) s += __shfl_xor(s, off);
    if (lane == 0) redsum[w] = s;
    __syncthreads();
    s = redsum[0] + redsum[1] + redsum[2] + redsum[3];
    float inv = 1.f / s;
#pragma unroll
    for (int i = 0; i < 17; ++i) {
        int mm = i * 256 + t;
        prow[mm] = f2bf(vals[i] * inv);   // mm max 4351 < NP; pads get 0
    }
}

// ---------------- K6: bilinear 2x upsample (exact) + gamma*val + x
__global__ __launch_bounds__(256) void upsample_add(const float* __restrict__ ctx,
                                                    const float* __restrict__ x,
                                                    const float* __restrict__ gm,
                                                    float* __restrict__ out) {
    size_t idx = (size_t)blockIdx.x * 256 + threadIdx.x;
    if (idx >= (size_t)OUTSZ) return;
    int xx = (int)(idx % WW);
    int yy = (int)((idx / WW) % HH);
    size_t bc = idx / (HH * WW);
    const float* cb = ctx + bc * NP;
    int i0 = yy >> 1, j0 = xx >> 1;
    int n00 = i0 * 65 + j0;
    float v;
    bool ye = !(yy & 1), xe = !(xx & 1);
    if (ye && xe)       v = cb[n00];
    else if (!ye && xe) v = 0.5f * (cb[n00] + cb[n00 + 65]);
    else if (ye)        v = 0.5f * (cb[n00] + cb[n00 + 1]);
    else                v = 0.25f * (cb[n00] + cb[n00 + 1] + cb[n00 + 65] + cb[n00 + 66]);
    out[idx] = gm[0] * v + x[idx];
}

// ---------------- workspace layout (bytes)
#define SZ_WC   ((size_t)640 * 512 * 2)
#define OFF_XST (SZ_WC)
#define SZ_XST  ((size_t)BB * NP * 512 * 2)
#define OFF_QKT (OFF_XST + SZ_XST)
#define SZ_QKT  ((size_t)BB * NP * 128 * 2)
#define OFF_V   (OFF_QKT + SZ_QKT)
#define SZ_V    ((size_t)BB * 512 * NP * 2)
#define OFF_CTX (OFF_V + SZ_V)
#define SZ_CTX  ((size_t)BB * 512 * NP * 4)
#define OFF_P   (OFF_CTX + SZ_CTX)

extern "C" void kernel_launch(void* const* d_in, const int* in_sizes, int n_in,
                              void* d_out, int out_size, void* d_ws, size_t ws_size,
                              hipStream_t stream) {
    const float* x  = (const float*)d_in[0];
    const float* Wq = (const float*)d_in[1];
    const float* bq = (const float*)d_in[2];
    const float* Wk = (const float*)d_in[3];
    const float* bk = (const float*)d_in[4];
    const float* Wv = (const float*)d_in[5];
    const float* bv = (const float*)d_in[6];
    const float* gm = (const float*)d_in[7];

    float* out = (float*)d_out;
    float* energy = out + (size_t)OUTSZ;

    char* ws = (char*)d_ws;
    u16* Wc  = (u16*)(ws);
    u16* XsT = (u16*)(ws + OFF_XST);
    u16* qkT = (u16*)(ws + OFF_QKT);
    u16* V   = (u16*)(ws + OFF_V);
    float* ctx = (float*)(ws + OFF_CTX);
    u16* P   = (u16*)(ws + OFF_P);

    cast_weights<<<1280, 256, 0, stream>>>(Wq, Wk, Wv, Wc);
    subsample_t<<<dim3(68, 8, BB), 256, 0, stream>>>(x, XsT);
    gemm_nt<0><<<dim3(34, 5, BB), 256, 0, stream>>>(Wc, XsT, 512, 512, 512,
                                                    nullptr, qkT, V, bq, bk, bv);
    gemm_nt<1><<<dim3(34, 34, BB), 256, 0, stream>>>(qkT, qkT, 64, 128, 128,
                                                     energy, nullptr, nullptr, nullptr, nullptr, nullptr);
    softmax_rows<<<dim3(NN, BB), 256, 0, stream>>>(energy, P);
    gemm_nt<2><<<dim3(34, 4, BB), 256, 0, stream>>>(V, P, NP, NP, NP,
                                                    ctx, nullptr, nullptr, nullptr, nullptr, nullptr);
    upsample_add<<<(OUTSZ + 255) / 256, 256, 0, stream>>>(ctx, x, gm, out);
}

// Round 2
// 526.065 us; speedup vs baseline: 1.1120x; 1.1120x over previous
//
#include <hip/hip_runtime.h>
#include <hip/hip_bf16.h>
#include <cstdint>

// Problem constants
#define BB 4
#define CC 512
#define CQK 64
#define HH 129
#define WW 129
#define HS 65
#define WSZ 65
#define NN 4225            // HS*WSZ
#define NP 4352            // padded N (34*128)
#define OUTSZ 34080768     // BB*CC*HH*WW
#define ESZ 17850625       // NN*NN

typedef unsigned short u16;
typedef __attribute__((ext_vector_type(8))) __bf16 bfrag;
typedef __attribute__((ext_vector_type(4))) float f4v;

__device__ inline u16 f2bf(float f) {
    union { float f; unsigned int u; } v; v.f = f;
    unsigned int u = v.u;
    return (u16)((u + 0x7FFFu + ((u >> 16) & 1u)) >> 16);
}

// async global->LDS, 16 bytes per lane; lds dest must be wave-uniform base
__device__ __forceinline__ void gload16(const u16* g, u16* l) {
    __builtin_amdgcn_global_load_lds(
        (const __attribute__((address_space(1))) void*)g,
        (__attribute__((address_space(3))) void*)l, 16, 0, 0);
}

// ---------------- K0: cast & pack weights [640][512] bf16 (q rows 0-63, k 64-127, v 128-639)
__global__ __launch_bounds__(256) void cast_weights(const float* __restrict__ Wq,
                                                    const float* __restrict__ Wk,
                                                    const float* __restrict__ Wv,
                                                    u16* __restrict__ Wc) {
    int idx = blockIdx.x * 256 + threadIdx.x;
    if (idx >= 640 * 512) return;
    int o = idx >> 9, c = idx & 511;
    float v = (o < 64) ? Wq[o * 512 + c] : (o < 128) ? Wk[(o - 64) * 512 + c] : Wv[(o - 128) * 512 + c];
    Wc[idx] = f2bf(v);
}

// ---------------- K1: subsample (exact stride-2) + transpose to XsT[b][n][c] bf16
__global__ __launch_bounds__(256) void subsample_t(const float* __restrict__ x, u16* __restrict__ XsT) {
    __shared__ u16 tile[64][65];
    int nt = blockIdx.x, ct = blockIdx.y, b = blockIdx.z;
    int t = threadIdx.x;
#pragma unroll
    for (int l = 0; l < 16; ++l) {
        int e = t + l * 256;
        int ci = e >> 6, nj = e & 63;
        int n = nt * 64 + nj;
        int nc = n < (NN - 1) ? n : (NN - 1);
        int i = nc / 65, j = nc % 65;
        int c = ct * 64 + ci;
        float v = x[(((size_t)b * CC + c) * HH + 2 * i) * WW + 2 * j];
        tile[ci][nj] = f2bf(v);
    }
    __syncthreads();
#pragma unroll
    for (int l = 0; l < 16; ++l) {
        int e = t + l * 256;
        int nj = e >> 6, ci = e & 63;
        XsT[((size_t)b * NP + nt * 64 + nj) * 512 + ct * 64 + ci] = tile[ci][nj];
    }
}

// ---------------- generic NT GEMM (m97 structure: global_load_lds staging, linear LDS)
// C[m][n] = sum_k A[m][k]*Bt[n][k]
// MODE 0: QKV  A=Wc[640][512], B=XsT[b], out -> qkT[n][o] (o<128) / V[o-128][n], +bias, bf16
// MODE 1: energy A=qkT[b] cols0-63, B=qkT[b] cols64-127, K=64,
//         out -> energy fp32 + Ptil bf16 (=exp(e), col-padded 0) + per-row partial sums
// MODE 2: PV   A=V[b][512][NP], B=Ptil[b][NP][NP], K=NP, out -> ctx fp32 [512][NP] scaled by invsum
template <int MODE>
__global__ __launch_bounds__(256) void gemm_nt(const u16* __restrict__ Abase,
                                               const u16* __restrict__ Bbase,
                                               int K, int lda, int ldb,
                                               float* __restrict__ outF,
                                               u16* __restrict__ out1, u16* __restrict__ out2,
                                               const float* __restrict__ bq,
                                               const float* __restrict__ bk,
                                               const float* __restrict__ bv,
                                               float* __restrict__ psums,
                                               const float* __restrict__ invsum) {
    __shared__ __align__(16) u16 As[128 * 64];   // linear row-major [128][64]
    __shared__ __align__(16) u16 Bs[128 * 64];

    const int z = blockIdx.z;
    const u16* A; const u16* Bm;
    if (MODE == 0) { A = Abase;                          Bm = Bbase + (size_t)z * NP * 512; }
    if (MODE == 1) { A = Abase + (size_t)z * NP * 128;   Bm = Bbase + (size_t)z * NP * 128 + 64; }
    if (MODE == 2) { A = Abase + (size_t)z * 512 * NP;   Bm = Bbase + (size_t)z * NP * NP; }

    const size_t m0 = (size_t)blockIdx.y * 128;
    const size_t n0 = (size_t)blockIdx.x * 128;
    const u16* Ab = A + m0 * lda;
    const u16* Bb = Bm + n0 * ldb;

    const int tid = threadIdx.x;
    const int lane = tid & 63, w = tid >> 6;
    const int wr = w >> 1, wc = w & 1;
    const int frow = lane & 15, fk = (lane >> 4) * 8;

    f4v acc[4][4];
#pragma unroll
    for (int i = 0; i < 4; ++i)
#pragma unroll
        for (int j = 0; j < 4; ++j) acc[i][j] = (f4v){0.f, 0.f, 0.f, 0.f};

    for (int kt = 0; kt < K; kt += 64) {
        if (kt) __syncthreads();   // protect LDS from readers of previous tile
        // stage A,B tiles: 1024 chunks of 16B each; wave-uniform LDS base + lane*16
#pragma unroll
        for (int it = 0; it < 4; ++it) {
            int cb = (it * 4 + w) * 64;          // wave-uniform chunk base
            int chunk = cb + lane;               // per-lane
            int r = chunk >> 3;
            int kc = (chunk & 7) << 3;
            gload16(Ab + (size_t)r * lda + kt + kc, &As[cb * 8]);
            gload16(Bb + (size_t)r * ldb + kt + kc, &Bs[cb * 8]);
        }
        __syncthreads();           // compiler drains vmcnt(0) before barrier
#pragma unroll
        for (int ks = 0; ks < 2; ++ks) {
            bfrag af[4], bf[4];
#pragma unroll
            for (int i = 0; i < 4; ++i)
                af[i] = *(const bfrag*)&As[(wr * 64 + i * 16 + frow) * 64 + ks * 32 + fk];
#pragma unroll
            for (int j = 0; j < 4; ++j)
                bf[j] = *(const bfrag*)&Bs[(wc * 64 + j * 16 + frow) * 64 + ks * 32 + fk];
#pragma unroll
            for (int i = 0; i < 4; ++i)
#pragma unroll
                for (int j = 0; j < 4; ++j)
                    acc[i][j] = __builtin_amdgcn_mfma_f32_16x16x32_bf16(af[i], bf[j], acc[i][j], 0, 0, 0);
        }
    }

    // ---------------- epilogue
    const int rbase = (lane >> 4) * 4, cbase = lane & 15;

    if (MODE == 0) {
        u16* out1b = out1 + (size_t)z * NP * 128;
        u16* out2b = out2 + (size_t)z * 512 * NP;
#pragma unroll
        for (int i = 0; i < 4; ++i)
#pragma unroll
            for (int j = 0; j < 4; ++j) {
                size_t row0 = m0 + wr * 64 + i * 16 + rbase;
                size_t col = n0 + wc * 64 + j * 16 + cbase;
#pragma unroll
                for (int r = 0; r < 4; ++r) {
                    int o = (int)(row0 + r);
                    float bias = (o < 64) ? bq[o] : (o < 128) ? bk[o - 64] : bv[o - 128];
                    u16 bb = f2bf(acc[i][j][r] + bias);
                    if (o < 128) out1b[col * 128 + o] = bb;
                    else out2b[(size_t)(o - 128) * NP + col] = bb;
                }
            }
    } else if (MODE == 1) {
        float* eb = outF + (size_t)z * ESZ;
        u16* Pb = out1 + (size_t)z * NP * NP;
        float psl[4][4];
#pragma unroll
        for (int i = 0; i < 4; ++i)
#pragma unroll
            for (int r = 0; r < 4; ++r) psl[i][r] = 0.f;
#pragma unroll
        for (int i = 0; i < 4; ++i)
#pragma unroll
            for (int j = 0; j < 4; ++j) {
                size_t row0 = m0 + wr * 64 + i * 16 + rbase;
                size_t col = n0 + wc * 64 + j * 16 + cbase;
#pragma unroll
                for (int r = 0; r < 4; ++r) {
                    float v = acc[i][j][r];
                    size_t ro = row0 + r;
                    float pe = (col < NN) ? __expf(v) : 0.f;
                    if (ro < NN && col < NN) eb[ro * NN + col] = v;
                    Pb[ro * NP + col] = f2bf(pe);
                    psl[i][r] += pe;
                }
            }
        // reduce partial sums across the 16 column-lanes (same rows)
        float* pbase = psums + ((size_t)z * 68 + blockIdx.x * 2 + wc) * NP;
#pragma unroll
        for (int i = 0; i < 4; ++i)
#pragma unroll
            for (int r = 0; r < 4; ++r) {
                float s = psl[i][r];
                s += __shfl_xor(s, 1);
                s += __shfl_xor(s, 2);
                s += __shfl_xor(s, 4);
                s += __shfl_xor(s, 8);
                if (cbase == 0)
                    pbase[m0 + wr * 64 + i * 16 + rbase + r] = s;
            }
    } else {
        float* outFb = outF + (size_t)z * 512 * NP;
        const float* isb = invsum + (size_t)z * NP;
#pragma unroll
        for (int j = 0; j < 4; ++j) {
            size_t col = n0 + wc * 64 + j * 16 + cbase;
            float inv = isb[col];
#pragma unroll
            for (int i = 0; i < 4; ++i) {
                size_t row0 = m0 + wr * 64 + i * 16 + rbase;
#pragma unroll
                for (int r = 0; r < 4; ++r)
                    outFb[(row0 + r) * NP + col] = acc[i][j][r] * inv;
            }
        }
    }
}

// ---------------- K5: reduce partial sums -> invsum[b][n]
__global__ __launch_bounds__(256) void reduce_sums(const float* __restrict__ psums,
                                                   float* __restrict__ invsum) {
    int idx = blockIdx.x * 256 + threadIdx.x;
    if (idx >= BB * NP) return;
    int b = idx / NP, n = idx % NP;
    const float* p = psums + (size_t)b * 68 * NP + n;
    float s = 0.f;
#pragma unroll
    for (int ct = 0; ct < 68; ++ct) s += p[(size_t)ct * NP];
    invsum[idx] = 1.f / s;
}

// ---------------- K6: bilinear 2x upsample (exact) + gamma*val + x
__global__ __launch_bounds__(256) void upsample_add(const float* __restrict__ ctx,
                                                    const float* __restrict__ x,
                                                    const float* __restrict__ gm,
                                                    float* __restrict__ out) {
    size_t idx = (size_t)blockIdx.x * 256 + threadIdx.x;
    if (idx >= (size_t)OUTSZ) return;
    int xx = (int)(idx % WW);
    int yy = (int)((idx / WW) % HH);
    size_t bc = idx / (HH * WW);
    const float* cb = ctx + bc * NP;
    int i0 = yy >> 1, j0 = xx >> 1;
    int n00 = i0 * 65 + j0;
    float v;
    bool ye = !(yy & 1), xe = !(xx & 1);
    if (ye && xe)       v = cb[n00];
    else if (!ye && xe) v = 0.5f * (cb[n00] + cb[n00 + 65]);
    else if (ye)        v = 0.5f * (cb[n00] + cb[n00 + 1]);
    else                v = 0.25f * (cb[n00] + cb[n00 + 1] + cb[n00 + 65] + cb[n00 + 66]);
    out[idx] = gm[0] * v + x[idx];
}

// ---------------- workspace layout (bytes)
#define SZ_WC   ((size_t)640 * 512 * 2)
#define OFF_XST (SZ_WC)
#define SZ_XST  ((size_t)BB * NP * 512 * 2)
#define OFF_QKT (OFF_XST + SZ_XST)
#define SZ_QKT  ((size_t)BB * NP * 128 * 2)
#define OFF_V   (OFF_QKT + SZ_QKT)
#define SZ_V    ((size_t)BB * 512 * NP * 2)
#define OFF_CTX (OFF_V + SZ_V)
#define SZ_CTX  ((size_t)BB * 512 * NP * 4)
#define OFF_P   (OFF_CTX + SZ_CTX)
#define SZ_P    ((size_t)BB * NP * NP * 2)
#define OFF_INV (OFF_P + SZ_P)

extern "C" void kernel_launch(void* const* d_in, const int* in_sizes, int n_in,
                              void* d_out, int out_size, void* d_ws, size_t ws_size,
                              hipStream_t stream) {
    const float* x  = (const float*)d_in[0];
    const float* Wq = (const float*)d_in[1];
    const float* bq = (const float*)d_in[2];
    const float* Wk = (const float*)d_in[3];
    const float* bk = (const float*)d_in[4];
    const float* Wv = (const float*)d_in[5];
    const float* bv = (const float*)d_in[6];
    const float* gm = (const float*)d_in[7];

    float* out = (float*)d_out;
    float* energy = out + (size_t)OUTSZ;

    char* ws = (char*)d_ws;
    u16* Wc  = (u16*)(ws);
    u16* XsT = (u16*)(ws + OFF_XST);
    u16* qkT = (u16*)(ws + OFF_QKT);
    u16* V   = (u16*)(ws + OFF_V);
    float* ctx = (float*)(ws + OFF_CTX);
    float* psums = ctx;                       // alias: psums dead before ctx written
    u16* P   = (u16*)(ws + OFF_P);
    float* invsum = (float*)(ws + OFF_INV);

    cast_weights<<<1280, 256, 0, stream>>>(Wq, Wk, Wv, Wc);
    subsample_t<<<dim3(68, 8, BB), 256, 0, stream>>>(x, XsT);
    gemm_nt<0><<<dim3(34, 5, BB), 256, 0, stream>>>(Wc, XsT, 512, 512, 512,
                                                    nullptr, qkT, V, bq, bk, bv, nullptr, nullptr);
    gemm_nt<1><<<dim3(34, 34, BB), 256, 0, stream>>>(qkT, qkT, 64, 128, 128,
                                                     energy, P, nullptr, nullptr, nullptr, nullptr,
                                                     psums, nullptr);
    reduce_sums<<<68, 256, 0, stream>>>(psums, invsum);
    gemm_nt<2><<<dim3(34, 4, BB), 256, 0, stream>>>(V, P, NP, NP, NP,
                                                    ctx, nullptr, nullptr, nullptr, nullptr, nullptr,
                                                    nullptr, invsum);
    upsample_add<<<(OUTSZ + 255) / 256, 256, 0, stream>>>(ctx, x, gm, out);
}

// Round 3
// 475.090 us; speedup vs baseline: 1.2313x; 1.1073x over previous
//
#include <hip/hip_runtime.h>
#include <hip/hip_bf16.h>
#include <cstdint>

// Problem constants
#define BB 4
#define CC 512
#define CQK 64
#define HH 129
#define WW 129
#define HS 65
#define WSZ 65
#define NN 4225            // HS*WSZ
#define NP 4352            // padded N (34*128)
#define KPV 4288           // 67 K-tiles of 64; P cols 4288.. are zero
#define OUTSZ 34080768     // BB*CC*HH*WW
#define ESZ 17850625       // NN*NN

typedef unsigned short u16;
typedef __attribute__((ext_vector_type(8))) __bf16 bfrag;
typedef __attribute__((ext_vector_type(4))) float f4v;

__device__ inline u16 f2bf(float f) {
    union { float f; unsigned int u; } v; v.f = f;
    unsigned int u = v.u;
    return (u16)((u + 0x7FFFu + ((u >> 16) & 1u)) >> 16);
}

// async global->LDS, 16 bytes per lane; lds dest must be wave-uniform base
__device__ __forceinline__ void gload16(const u16* g, u16* l) {
    __builtin_amdgcn_global_load_lds(
        (const __attribute__((address_space(1))) void*)g,
        (__attribute__((address_space(3))) void*)l, 16, 0, 0);
}

// ---------------- K0: cast & pack weights [640][512] bf16 (q rows 0-63, k 64-127, v 128-639)
__global__ __launch_bounds__(256) void cast_weights(const float* __restrict__ Wq,
                                                    const float* __restrict__ Wk,
                                                    const float* __restrict__ Wv,
                                                    u16* __restrict__ Wc) {
    int idx = blockIdx.x * 256 + threadIdx.x;
    if (idx >= 640 * 512) return;
    int o = idx >> 9, c = idx & 511;
    float v = (o < 64) ? Wq[o * 512 + c] : (o < 128) ? Wk[(o - 64) * 512 + c] : Wv[(o - 128) * 512 + c];
    Wc[idx] = f2bf(v);
}

// ---------------- K1: subsample (exact stride-2) + transpose to XsT[b][n][c] bf16
__global__ __launch_bounds__(256) void subsample_t(const float* __restrict__ x, u16* __restrict__ XsT) {
    __shared__ u16 tile[64][65];
    int nt = blockIdx.x, ct = blockIdx.y, b = blockIdx.z;
    int t = threadIdx.x;
#pragma unroll
    for (int l = 0; l < 16; ++l) {
        int e = t + l * 256;
        int ci = e >> 6, nj = e & 63;
        int n = nt * 64 + nj;
        int nc = n < (NN - 1) ? n : (NN - 1);
        int i = nc / 65, j = nc % 65;
        int c = ct * 64 + ci;
        float v = x[(((size_t)b * CC + c) * HH + 2 * i) * WW + 2 * j];
        tile[ci][nj] = f2bf(v);
    }
    __syncthreads();
#pragma unroll
    for (int l = 0; l < 16; ++l) {
        int e = t + l * 256;
        int nj = e >> 6, ci = e & 63;
        XsT[((size_t)b * NP + nt * 64 + nj) * 512 + ct * 64 + ci] = tile[ci][nj];
    }
}

// ---------------- generic NT GEMM (m97 structure)
// MODE 0: QKV  A=Wc[640][512], B=XsT[b], out -> qkT[n][o] (o<128) / V[o-128][n], +bias, bf16
// MODE 1: energy A=qkT[b] cols0-63, B=qkT[b] cols64-127, K=64,
//         out -> energy fp32 + Ptil bf16 (=exp(e), col-padded 0) + per-row partial sums
template <int MODE>
__global__ __launch_bounds__(256) void gemm_nt(const u16* __restrict__ Abase,
                                               const u16* __restrict__ Bbase,
                                               int K, int lda, int ldb,
                                               float* __restrict__ outF,
                                               u16* __restrict__ out1, u16* __restrict__ out2,
                                               const float* __restrict__ bq,
                                               const float* __restrict__ bk,
                                               const float* __restrict__ bv,
                                               float* __restrict__ psums) {
    __shared__ __align__(16) u16 As[128 * 64];
    __shared__ __align__(16) u16 Bs[128 * 64];

    const int z = blockIdx.z;
    const u16* A; const u16* Bm;
    if (MODE == 0) { A = Abase;                          Bm = Bbase + (size_t)z * NP * 512; }
    if (MODE == 1) { A = Abase + (size_t)z * NP * 128;   Bm = Bbase + (size_t)z * NP * 128 + 64; }

    const size_t m0 = (size_t)blockIdx.y * 128;
    const size_t n0 = (size_t)blockIdx.x * 128;
    const u16* Ab = A + m0 * lda;
    const u16* Bb = Bm + n0 * ldb;

    const int tid = threadIdx.x;
    const int lane = tid & 63, w = tid >> 6;
    const int wr = w >> 1, wc = w & 1;
    const int frow = lane & 15, fk = (lane >> 4) * 8;

    f4v acc[4][4];
#pragma unroll
    for (int i = 0; i < 4; ++i)
#pragma unroll
        for (int j = 0; j < 4; ++j) acc[i][j] = (f4v){0.f, 0.f, 0.f, 0.f};

    for (int kt = 0; kt < K; kt += 64) {
        if (kt) __syncthreads();
#pragma unroll
        for (int it = 0; it < 4; ++it) {
            int cb = (it * 4 + w) * 64;
            int chunk = cb + lane;
            int r = chunk >> 3;
            int kc = (chunk & 7) << 3;
            gload16(Ab + (size_t)r * lda + kt + kc, &As[cb * 8]);
            gload16(Bb + (size_t)r * ldb + kt + kc, &Bs[cb * 8]);
        }
        __syncthreads();
#pragma unroll
        for (int ks = 0; ks < 2; ++ks) {
            bfrag af[4], bf[4];
#pragma unroll
            for (int i = 0; i < 4; ++i)
                af[i] = *(const bfrag*)&As[(wr * 64 + i * 16 + frow) * 64 + ks * 32 + fk];
#pragma unroll
            for (int j = 0; j < 4; ++j)
                bf[j] = *(const bfrag*)&Bs[(wc * 64 + j * 16 + frow) * 64 + ks * 32 + fk];
#pragma unroll
            for (int i = 0; i < 4; ++i)
#pragma unroll
                for (int j = 0; j < 4; ++j)
                    acc[i][j] = __builtin_amdgcn_mfma_f32_16x16x32_bf16(af[i], bf[j], acc[i][j], 0, 0, 0);
        }
    }

    const int rbase = (lane >> 4) * 4, cbase = lane & 15;

    if (MODE == 0) {
        u16* out1b = out1 + (size_t)z * NP * 128;
        u16* out2b = out2 + (size_t)z * 512 * NP;
#pragma unroll
        for (int i = 0; i < 4; ++i)
#pragma unroll
            for (int j = 0; j < 4; ++j) {
                size_t row0 = m0 + wr * 64 + i * 16 + rbase;
                size_t col = n0 + wc * 64 + j * 16 + cbase;
#pragma unroll
                for (int r = 0; r < 4; ++r) {
                    int o = (int)(row0 + r);
                    float bias = (o < 64) ? bq[o] : (o < 128) ? bk[o - 64] : bv[o - 128];
                    u16 bb = f2bf(acc[i][j][r] + bias);
                    if (o < 128) out1b[col * 128 + o] = bb;
                    else out2b[(size_t)(o - 128) * NP + col] = bb;
                }
            }
    } else {
        float* eb = outF + (size_t)z * ESZ;
        u16* Pb = out1 + (size_t)z * NP * NP;
        float psl[4][4];
#pragma unroll
        for (int i = 0; i < 4; ++i)
#pragma unroll
            for (int r = 0; r < 4; ++r) psl[i][r] = 0.f;
#pragma unroll
        for (int i = 0; i < 4; ++i)
#pragma unroll
            for (int j = 0; j < 4; ++j) {
                size_t row0 = m0 + wr * 64 + i * 16 + rbase;
                size_t col = n0 + wc * 64 + j * 16 + cbase;
#pragma unroll
                for (int r = 0; r < 4; ++r) {
                    float v = acc[i][j][r];
                    size_t ro = row0 + r;
                    float pe = (col < NN) ? __expf(v) : 0.f;
                    if (ro < NN && col < NN) eb[ro * NN + col] = v;
                    Pb[ro * NP + col] = f2bf(pe);
                    psl[i][r] += pe;
                }
            }
        float* pbase = psums + ((size_t)z * 68 + blockIdx.x * 2 + wc) * NP;
#pragma unroll
        for (int i = 0; i < 4; ++i)
#pragma unroll
            for (int r = 0; r < 4; ++r) {
                float s = psl[i][r];
                s += __shfl_xor(s, 1);
                s += __shfl_xor(s, 2);
                s += __shfl_xor(s, 4);
                s += __shfl_xor(s, 8);
                if (cbase == 0)
                    pbase[m0 + wr * 64 + i * 16 + rbase + r] = s;
            }
    }
}

// ---------------- K5: reduce partial sums -> invsum[b][n]
__global__ __launch_bounds__(256) void reduce_sums(const float* __restrict__ psums,
                                                   float* __restrict__ invsum) {
    int idx = blockIdx.x * 256 + threadIdx.x;
    if (idx >= BB * NP) return;
    int b = idx / NP, n = idx % NP;
    const float* p = psums + (size_t)b * 68 * NP + n;
    float s = 0.f;
#pragma unroll
    for (int ct = 0; ct < 68; ++ct) s += p[(size_t)ct * NP];
    invsum[idx] = 1.f / s;
}

// ---------------- PV GEMM: split-K x2 + bijective XCD swizzle
// ctx_h[c][n] = invsum[n] * sum_{m in half} V[c][m] * Ptil[n][m]
__global__ __launch_bounds__(256) void gemm_pv(const u16* __restrict__ Vb,
                                               const u16* __restrict__ P,
                                               float* __restrict__ ctx0,
                                               float* __restrict__ ctx1,
                                               const float* __restrict__ invsum) {
    __shared__ __align__(16) u16 As[128 * 64];
    __shared__ __align__(16) u16 Bs[128 * 64];

    // grid (34,4,8): nwg = 1088 = 8*136; XCD k gets one contiguous (batch,half) slice
    unsigned flat = blockIdx.x + 34u * (blockIdx.y + 4u * blockIdx.z);
    unsigned swz = (flat & 7u) * 136u + (flat >> 3);
    unsigned zs = swz / 136u;
    unsigned rem = swz - zs * 136u;
    unsigned ys = rem / 34u;
    unsigned xs = rem - ys * 34u;
    const int b = (int)(zs >> 1), half = (int)(zs & 1);

    const u16* A = Vb + (size_t)b * 512 * NP;
    const u16* Bm = P + (size_t)b * NP * NP;
    const size_t m0 = (size_t)ys * 128;
    const size_t n0 = (size_t)xs * 128;
    const u16* Ab = A + m0 * NP;
    const u16* Bb = Bm + n0 * NP;
    const int kbeg = half ? 2176 : 0;
    const int kend = half ? KPV : 2176;

    const int tid = threadIdx.x;
    const int lane = tid & 63, w = tid >> 6;
    const int wr = w >> 1, wc = w & 1;
    const int frow = lane & 15, fk = (lane >> 4) * 8;

    f4v acc[4][4];
#pragma unroll
    for (int i = 0; i < 4; ++i)
#pragma unroll
        for (int j = 0; j < 4; ++j) acc[i][j] = (f4v){0.f, 0.f, 0.f, 0.f};

    for (int kt = kbeg; kt < kend; kt += 64) {
        if (kt != kbeg) __syncthreads();
#pragma unroll
        for (int it = 0; it < 4; ++it) {
            int cb = (it * 4 + w) * 64;
            int chunk = cb + lane;
            int r = chunk >> 3;
            int kc = (chunk & 7) << 3;
            gload16(Ab + (size_t)r * NP + kt + kc, &As[cb * 8]);
            gload16(Bb + (size_t)r * NP + kt + kc, &Bs[cb * 8]);
        }
        __syncthreads();
#pragma unroll
        for (int ks = 0; ks < 2; ++ks) {
            bfrag af[4], bf[4];
#pragma unroll
            for (int i = 0; i < 4; ++i)
                af[i] = *(const bfrag*)&As[(wr * 64 + i * 16 + frow) * 64 + ks * 32 + fk];
#pragma unroll
            for (int j = 0; j < 4; ++j)
                bf[j] = *(const bfrag*)&Bs[(wc * 64 + j * 16 + frow) * 64 + ks * 32 + fk];
#pragma unroll
            for (int i = 0; i < 4; ++i)
#pragma unroll
                for (int j = 0; j < 4; ++j)
                    acc[i][j] = __builtin_amdgcn_mfma_f32_16x16x32_bf16(af[i], bf[j], acc[i][j], 0, 0, 0);
        }
    }

    const int rbase = (lane >> 4) * 4, cbase = lane & 15;
    float* outFb = (half ? ctx1 : ctx0) + (size_t)b * 512 * NP;
    const float* isb = invsum + (size_t)b * NP;
#pragma unroll
    for (int j = 0; j < 4; ++j) {
        size_t col = n0 + wc * 64 + j * 16 + cbase;
        float inv = isb[col];
#pragma unroll
        for (int i = 0; i < 4; ++i) {
            size_t row0 = m0 + wr * 64 + i * 16 + rbase;
#pragma unroll
            for (int r = 0; r < 4; ++r)
                outFb[(row0 + r) * NP + col] = acc[i][j][r] * inv;
        }
    }
}

// ---------------- K6: bilinear 2x upsample, branchless + float4 streams
__global__ __launch_bounds__(256) void upsample_add(const float* __restrict__ ctx0,
                                                    const float* __restrict__ ctx1,
                                                    const float* __restrict__ x,
                                                    const float* __restrict__ gm,
                                                    float* __restrict__ out) {
    unsigned q = blockIdx.x * 256 + threadIdx.x;
    if (q >= (OUTSZ / 4)) return;
    unsigned idx0 = q * 4;
    float g = gm[0];
    float4 xv = *(const float4*)&x[idx0];
    float ov[4];
#pragma unroll
    for (int e = 0; e < 4; ++e) {
        unsigned idx = idx0 + e;
        unsigned xx = idx % WW;
        unsigned t = idx / WW;
        unsigned yy = t % HH;
        unsigned bc = t / HH;
        const float* cA = ctx0 + (size_t)bc * NP;
        const float* cB = ctx1 + (size_t)bc * NP;
        unsigned i0 = yy >> 1, j0 = xx >> 1;
        unsigned n00 = i0 * 65 + j0;
        float wy = 0.5f * (float)(yy & 1), wx = 0.5f * (float)(xx & 1);
        float c00 = cA[n00] + cB[n00];
        float c01 = cA[n00 + 1] + cB[n00 + 1];
        float c10 = cA[n00 + 65] + cB[n00 + 65];
        float c11 = cA[n00 + 66] + cB[n00 + 66];
        float cx0 = c00 + wx * (c01 - c00);
        float cx1 = c10 + wx * (c11 - c10);
        ov[e] = g * (cx0 + wy * (cx1 - cx0));
    }
    float4 o4 = {ov[0] + xv.x, ov[1] + xv.y, ov[2] + xv.z, ov[3] + xv.w};
    *(float4*)&out[idx0] = o4;
}

// ---------------- workspace layout (bytes)
#define SZ_WC   ((size_t)640 * 512 * 2)
#define OFF_XST (SZ_WC)
#define SZ_XST  ((size_t)BB * NP * 512 * 2)
#define OFF_QKT (OFF_XST + SZ_XST)
#define SZ_QKT  ((size_t)BB * NP * 128 * 2)
#define OFF_V   (OFF_QKT + SZ_QKT)
#define SZ_V    ((size_t)BB * 512 * NP * 2)
#define OFF_CTX (OFF_V + SZ_V)
#define SZ_CTX  ((size_t)BB * 512 * NP * 4)
#define OFF_P   (OFF_CTX + SZ_CTX)
#define SZ_P    ((size_t)BB * NP * NP * 2)
#define OFF_INV (OFF_P + SZ_P)
#define SZ_INV  ((size_t)BB * NP * 4)
#define OFF_CTX2 (OFF_INV + SZ_INV)

extern "C" void kernel_launch(void* const* d_in, const int* in_sizes, int n_in,
                              void* d_out, int out_size, void* d_ws, size_t ws_size,
                              hipStream_t stream) {
    const float* x  = (const float*)d_in[0];
    const float* Wq = (const float*)d_in[1];
    const float* bq = (const float*)d_in[2];
    const float* Wk = (const float*)d_in[3];
    const float* bk = (const float*)d_in[4];
    const float* Wv = (const float*)d_in[5];
    const float* bv = (const float*)d_in[6];
    const float* gm = (const float*)d_in[7];

    float* out = (float*)d_out;
    float* energy = out + (size_t)OUTSZ;

    char* ws = (char*)d_ws;
    u16* Wc  = (u16*)(ws);
    u16* XsT = (u16*)(ws + OFF_XST);
    u16* qkT = (u16*)(ws + OFF_QKT);
    u16* V   = (u16*)(ws + OFF_V);
    float* ctx0 = (float*)(ws + OFF_CTX);
    float* psums = ctx0;                      // alias: psums dead before ctx0 written
    u16* P   = (u16*)(ws + OFF_P);
    float* invsum = (float*)(ws + OFF_INV);
    float* ctx1 = (float*)(ws + OFF_CTX2);

    cast_weights<<<1280, 256, 0, stream>>>(Wq, Wk, Wv, Wc);
    subsample_t<<<dim3(68, 8, BB), 256, 0, stream>>>(x, XsT);
    gemm_nt<0><<<dim3(34, 5, BB), 256, 0, stream>>>(Wc, XsT, 512, 512, 512,
                                                    nullptr, qkT, V, bq, bk, bv, nullptr);
    gemm_nt<1><<<dim3(34, 34, BB), 256, 0, stream>>>(qkT, qkT, 64, 128, 128,
                                                     energy, P, nullptr, nullptr, nullptr, nullptr,
                                                     psums);
    reduce_sums<<<68, 256, 0, stream>>>(psums, invsum);
    gemm_pv<<<dim3(34, 4, 8), 256, 0, stream>>>(V, P, ctx0, ctx1, invsum);
    upsample_add<<<(OUTSZ / 4 + 255) / 256, 256, 0, stream>>>(ctx0, ctx1, x, gm, out);
}